// Round 4
// baseline (330.173 us; speedup 1.0000x reference)
//
#include <hip/hip_runtime.h>

// LIF neuron scan: 16384 neurons x 2048 sequential steps, 1 thread/neuron,
// 256 waves = 1 wave/CU (structural).
//
// R3 (register ring) was vmcnt-capped: <=63 outstanding VMEM ops/wave at
// 256 B per dword-load => ~4 MB chip-wide in flight => ~3.8 TB/s effective.
//
// R4/R5 (LDS ring via __builtin_amdgcn_global_load_lds) regressed to 129 us:
// LLVM SIInsertWaitcnt cannot disambiguate LDS-DMA destinations vs ds_read
// at MIR level and inserts a conservative vmcnt drain per stage -> pipeline
// collapses to 1 HBM round trip per stage (512 x 250 ns).
//
// R6: DMA as inline asm (compiler inserts no waits; ordering carried by the
// manual counted s_waitcnt vmcnt(K) ramp, steady K = 3*(P-1) = 39, never 0).
// R6 DEFECT: clobbered m0 without restoring. gfx9-lineage DS instructions
// bounds-check LDS addresses against m0 (backend invariant: m0 = -1 from the
// kernel prologue); leaving m0 at a ring offset corrupts every compiler
// ds_read/ds_write after the first DMA. m0 is latched at DMA issue (the
// builtin's own lowering emits back-to-back s_mov m0 + load with no waits),
// so R7 restores m0 = -1 inside the same asm block, right after issue.
//
// Per-instr payload: 1 KB (64 lanes x 16 B). In-flight ~26 KB/wave x 256
// waves = 6.6 MB => latency-covered up to ~7 TB/s.
//
// Exactness (binary spike output): contract(off), reference op order:
//   V = (V + 0.05f*(I-V)) + nz ; s = V>=Vth ; V = s?0:V ;
//   Vth = s ? min(max(Vth+0.1f,0.5f),2.0f) : Vth

constexpr int N = 16384;    // neurons
constexpr int T = 2048;     // sequential steps
constexpr int U = 4;        // timesteps per chunk (one 1KB DMA per stream)
constexpr int C = T / U;    // 512 chunks
constexpr int R = 16;       // LDS ring slots (32 KB payload)
constexpr int P = 14;       // prefetch distance in chunks (26 KB in flight)

static_assert(C == 512 && R == 16 && P <= R - 2, "schedule geometry");

typedef float f4v __attribute__((ext_vector_type(4)));

// LDS byte offset (workgroup-relative) of a shared-memory pointer.
__device__ __forceinline__ unsigned lds_off(const void* p) {
    return (unsigned)(size_t)(const __attribute__((address_space(3))) void*)p;
}

// Async global->LDS DMA, 16 B/lane, hidden from the compiler's waitcnt pass.
// LDS destination = m0 (wave-uniform, latched at issue); lane l writes bytes
// [16l, 16l+16). m0 is restored to -1 (the backend's DS-limit invariant)
// immediately after issue.
__device__ __forceinline__ void dma16(const float* g, unsigned lds) {
    asm volatile(
        "s_mov_b32 m0, %1\n\t"
        "global_load_lds_dwordx4 %0, off\n\t"
        "s_mov_b32 m0, -1"
        :: "v"(g), "s"(lds) : "memory");
}

#define WAITV(K) asm volatile("s_waitcnt vmcnt(" #K ")" ::: "memory")

__global__
__attribute__((amdgpu_flat_work_group_size(64, 64)))
void TorchLIFNeuronGroup_85152021610615_kernel(const float* __restrict__ I,
                                               const float* __restrict__ Z,
                                               float* __restrict__ O) {
    #pragma clang fp contract(off)
    // ring[slot][stream][row][neuron]; each (slot,stream) chunk is one
    // contiguous 1 KB DMA destination (lane*16B linear).
    __shared__ __align__(16) float ring[R][2][U][64];
    __shared__ __align__(16) float sbuf[U][64];   // spike transpose buffer

    const int lane = threadIdx.x;
    const int g    = lane >> 4;          // row within chunk (0..3)
    const int c4   = (lane & 15) << 2;   // col group (0,4,..,60)
    const size_t laneOff = (size_t)g * N + c4;

    const float* ipfx = I + (size_t)blockIdx.x * 64 + laneOff;
    const float* zpfx = Z + (size_t)blockIdx.x * 64 + laneOff;
    float*       opfx = O + (size_t)blockIdx.x * 64 + laneOff;

    const unsigned rb = lds_off(&ring[0][0][0][0]);  // ring base (bytes)

    float V   = 0.0f;   // V_RESET
    float Vth = 1.0f;   // V_TH0

    // Prologue: DMA chunks 0..P-1 into slots 0..P-1 (chunk-major order).
    #pragma unroll
    for (int c = 0; c < P; ++c) {
        dma16(ipfx + (size_t)(c * U) * N, rb + (unsigned)(c * 2 + 0) * 1024u);
        dma16(zpfx + (size_t)(c * U) * N, rb + (unsigned)(c * 2 + 1) * 1024u);
    }

    int t = 0;  // timestep base of the chunk being computed

    // Stage: counted wait -> compute 4 steps from LDS -> spike transpose ->
    // one float4 NT store -> prefetch chunk t/U+P into slot (d+P)%R.
    // Steady-state vmem per stage = 2 DMA + 1 store = 3.
#define STAGE(d, K, PF)                                                       \
    {                                                                         \
        WAITV(K);                                                             \
        _Pragma("unroll")                                                     \
        for (int u = 0; u < U; ++u) {                                         \
            float Iv = ring[d][0][u][lane];                                   \
            float Zv = ring[d][1][u][lane];                                   \
            float dd = Iv - V;                                                \
            float v1 = V + 0.05f * dd;          /* DT/TAU */                  \
            float v2 = v1 + Zv;                                               \
            bool  s  = (v2 >= Vth);                                           \
            V = s ? 0.0f : v2;                                                \
            float nth = fminf(fmaxf(Vth + 0.1f, 0.5f), 2.0f);                 \
            Vth = s ? nth : Vth;                                              \
            sbuf[u][lane] = s ? 1.0f : 0.0f;                                  \
        }                                                                     \
        {                                                                     \
            f4v sv = *reinterpret_cast<const f4v*>(&sbuf[g][c4]);             \
            __builtin_nontemporal_store(                                      \
                sv, reinterpret_cast<f4v*>(opfx + (size_t)t * N));            \
        }                                                                     \
        if (PF) {                                                             \
            dma16(ipfx + (size_t)(t + P * U) * N,                             \
                  rb + (unsigned)((((d) + P) & (R - 1)) * 2 + 0) * 1024u);    \
            dma16(zpfx + (size_t)(t + P * U) * N,                             \
                  rb + (unsigned)((((d) + P) & (R - 1)) * 2 + 1) * 1024u);    \
        }                                                                     \
        __builtin_amdgcn_sched_barrier(0);                                    \
        t += U;                                                               \
    }

    // Iteration 0 (stages 0..15): ramped waits K(s) = 26+s up to steady 39.
    STAGE(0, 26, 1)  STAGE(1, 27, 1)  STAGE(2, 28, 1)  STAGE(3, 29, 1)
    STAGE(4, 30, 1)  STAGE(5, 31, 1)  STAGE(6, 32, 1)  STAGE(7, 33, 1)
    STAGE(8, 34, 1)  STAGE(9, 35, 1)  STAGE(10, 36, 1) STAGE(11, 37, 1)
    STAGE(12, 38, 1) STAGE(13, 39, 1) STAGE(14, 39, 1) STAGE(15, 39, 1)

    // Steady iterations 1..30 (stages 16..495): all K=39, all prefetch.
    for (int it = 1; it <= 30; ++it) {
        STAGE(0, 39, 1)  STAGE(1, 39, 1)  STAGE(2, 39, 1)  STAGE(3, 39, 1)
        STAGE(4, 39, 1)  STAGE(5, 39, 1)  STAGE(6, 39, 1)  STAGE(7, 39, 1)
        STAGE(8, 39, 1)  STAGE(9, 39, 1)  STAGE(10, 39, 1) STAGE(11, 39, 1)
        STAGE(12, 39, 1) STAGE(13, 39, 1) STAGE(14, 39, 1) STAGE(15, 39, 1)
    }

    // Last iteration (stages 496..511): prefetch stops at chunk 511 (stage
    // 497); waits ramp down exactly: K = 13 + 2*(511 - s) for s >= 498.
    STAGE(0, 39, 1)  STAGE(1, 39, 1)
    STAGE(2, 39, 0)  STAGE(3, 37, 0)  STAGE(4, 35, 0)  STAGE(5, 33, 0)
    STAGE(6, 31, 0)  STAGE(7, 29, 0)  STAGE(8, 27, 0)  STAGE(9, 25, 0)
    STAGE(10, 23, 0) STAGE(11, 21, 0) STAGE(12, 19, 0) STAGE(13, 17, 0)
    STAGE(14, 15, 0) STAGE(15, 13, 0)

#undef STAGE
}

extern "C" void kernel_launch(void* const* d_in, const int* in_sizes, int n_in,
                              void* d_out, int out_size, void* d_ws, size_t ws_size,
                              hipStream_t stream) {
    const float* input_current = (const float*)d_in[0];
    const float* noise         = (const float*)d_in[1];
    float* out                 = (float*)d_out;

    TorchLIFNeuronGroup_85152021610615_kernel<<<N / 64, 64, 0, stream>>>(
        input_current, noise, out);
}

// Round 5
// 314.940 us; speedup vs baseline: 1.0484x; 1.0484x over previous
//
#include <hip/hip_runtime.h>

// LIF neuron scan: 16384 neurons x 2048 sequential steps, 1 thread/neuron,
// 256 waves = 1 wave/CU (structural; time is a serial scan, neurons = 16384
// lanes exactly).
//
// History:
//  R3  register ring, 106 us: vmcnt-capped (<=63 dword loads in flight/wave
//      => ~4 MB chip-wide => ~3.8 TB/s effective ceiling).
//  R4/5 LDS ring via builtin global_load_lds, 129 us: SIInsertWaitcnt can't
//      disambiguate LDS-DMA vs ds_read and drains vmcnt per stage.
//  R6  inline-asm DMA, hung: clobbered m0 (DS address-limit invariant).
//  R7  m0 restored, correct but 144 us: WAITV never stalls (28 KB/wave in
//      flight = 7.2 MB chip-wide > 6.3 MB Little's-law need); the wave stalls
//      on IN-STAGE serial LDS latency with 1 wave/SIMD: ds_read ring (~120cy)
//      -> 4-step VALU chain (~100cy) -> sbuf write->b128-read round trip
//      (~180cy) -> store -> DMA  ~= 660 cy = 281 ns/stage * 512 = 144 us.
//
// R8: cross-stage software pipeline; LDS off the critical path:
//  - ring ds_reads for chunk d+1 issued at stage d into ping-pong regs
//    (rr[2][8]); compute chunk d uses regs loaded LAST stage -> ds_read
//    latency hidden under compute.
//  - sbuf double-buffered; stage d b128-reads sbuf[(d+1)&1] (chunk d-1,
//    written last stage; same-wave in-order LDS needs no barrier) and
//    NT-stores chunk d-1 -> write->read round trip spans a stage boundary.
//  - critical path/stage = 4-step dependent VALU chain + issue bw
//    (~150 cy) => ~35-40 us compute-side vs 43 us HBM floor (268 MB).
//  vmcnt (3 vmem ops/stage: 1 store + 2 DMA, store lags one stage):
//    steady K = 3*(P-2) = 36; prologue ramp K = 23+d (d=1..12, d0=24);
//    tail K = 1032-2d (d=499..510); last stage waits nothing.
//
// Exactness (binary spike output): contract(off), reference op order:
//   V = (V + 0.05f*(I-V)) + nz ; s = V>=Vth ; V = s?0:V ;
//   Vth = s ? min(max(Vth+0.1f,0.5f),2.0f) : Vth

constexpr int N = 16384;    // neurons
constexpr int T = 2048;     // sequential steps
constexpr int U = 4;        // timesteps per chunk (one 1KB DMA per stream)
constexpr int C = T / U;    // 512 chunks
constexpr int R = 16;       // LDS ring slots (32 KB payload)
constexpr int P = 14;       // prefetch distance in chunks (28 KB in flight)

static_assert(C == 512 && R == 16 && P <= R - 2, "schedule geometry");

typedef float f4v __attribute__((ext_vector_type(4)));

// LDS byte offset (workgroup-relative) of a shared-memory pointer.
__device__ __forceinline__ unsigned lds_off(const void* p) {
    return (unsigned)(size_t)(const __attribute__((address_space(3))) void*)p;
}

// Async global->LDS DMA, 16 B/lane, hidden from the compiler's waitcnt pass.
// LDS destination = m0 (wave-uniform, latched at issue); lane l writes bytes
// [16l, 16l+16). m0 restored to -1 (backend DS-limit invariant) after issue.
__device__ __forceinline__ void dma16(const float* g, unsigned lds) {
    asm volatile(
        "s_mov_b32 m0, %1\n\t"
        "global_load_lds_dwordx4 %0, off\n\t"
        "s_mov_b32 m0, -1"
        :: "v"(g), "s"(lds) : "memory");
}

#define WAITV(K) asm volatile("s_waitcnt vmcnt(" #K ")" ::: "memory")

__global__
__attribute__((amdgpu_flat_work_group_size(64, 64)))
void TorchLIFNeuronGroup_85152021610615_kernel(const float* __restrict__ I,
                                               const float* __restrict__ Z,
                                               float* __restrict__ O) {
    #pragma clang fp contract(off)
    // ring[slot][stream][row][neuron]; each (slot,stream) chunk is one
    // contiguous 1 KB DMA destination (lane*16B linear).
    __shared__ __align__(16) float ring[R][2][U][64];
    __shared__ __align__(16) float sbuf[2][U][64];  // spike transpose, 2-deep

    const int lane = threadIdx.x;
    const int g    = lane >> 4;          // row within chunk (0..3)
    const int c4   = (lane & 15) << 2;   // col group (0,4,..,60)
    const size_t laneOff = (size_t)g * N + c4;

    const float* ipfx = I + (size_t)blockIdx.x * 64 + laneOff;
    const float* zpfx = Z + (size_t)blockIdx.x * 64 + laneOff;
    float*       opfx = O + (size_t)blockIdx.x * 64 + laneOff;

    const unsigned rb = lds_off(&ring[0][0][0][0]);  // ring base (bytes)

    float V   = 0.0f;   // V_RESET
    float Vth = 1.0f;   // V_TH0
    float rr[2][8];     // ping-pong chunk regs: [set][I0..3, Z0..3]

    // Prologue: DMA chunks 0..P-1 into slots 0..P-1 (chunk-major order),
    // then pre-load chunk 0 into reg set 0 (chunk 0's Z-DMA is op #2 of 28
    // outstanding -> WAITV(26)).
    #pragma unroll
    for (int c = 0; c < P; ++c) {
        dma16(ipfx + (size_t)(c * U) * N, rb + (unsigned)(c * 2 + 0) * 1024u);
        dma16(zpfx + (size_t)(c * U) * N, rb + (unsigned)(c * 2 + 1) * 1024u);
    }
    WAITV(26);
    #pragma unroll
    for (int u = 0; u < U; ++u) {
        rr[0][u]     = ring[0][0][u][lane];
        rr[0][4 + u] = ring[0][1][u][lane];
    }

    int t = 0;  // timestep base of the chunk being computed

    // Stage d: [WAITV(K): chunk d+1 DMAs complete] -> issue b128 read of
    // chunk d-1's spikes (ST) -> issue 8 ring ds_reads for chunk d+1 (LD) ->
    // compute chunk d from regs (loaded last stage) -> write spikes to
    // sbuf[d&1] -> NT-store chunk d-1 (ST) -> DMA chunk d+P (PF).
#define STAGE_BODY(d, PF, LD, ST)                                             \
    {                                                                         \
        f4v sv{};                                                             \
        if (ST) sv = *reinterpret_cast<const f4v*>(&sbuf[((d) + 1) & 1][g][c4]); \
        if (LD) {                                                             \
            _Pragma("unroll")                                                 \
            for (int u = 0; u < U; ++u) {                                     \
                rr[((d) + 1) & 1][u]     = ring[((d) + 1) & (R - 1)][0][u][lane]; \
                rr[((d) + 1) & 1][4 + u] = ring[((d) + 1) & (R - 1)][1][u][lane]; \
            }                                                                 \
        }                                                                     \
        _Pragma("unroll")                                                     \
        for (int u = 0; u < U; ++u) {                                         \
            float Iv = rr[(d) & 1][u];                                        \
            float Zv = rr[(d) & 1][4 + u];                                    \
            float dd = Iv - V;                                                \
            float v1 = V + 0.05f * dd;          /* DT/TAU */                  \
            float v2 = v1 + Zv;                                               \
            bool  s  = (v2 >= Vth);                                           \
            V = s ? 0.0f : v2;                                                \
            float nth = fminf(fmaxf(Vth + 0.1f, 0.5f), 2.0f);                 \
            Vth = s ? nth : Vth;                                              \
            sbuf[(d) & 1][u][lane] = s ? 1.0f : 0.0f;                         \
        }                                                                     \
        if (ST) __builtin_nontemporal_store(                                  \
                    sv, reinterpret_cast<f4v*>(opfx + (size_t)(t - U) * N));  \
        if (PF) {                                                             \
            dma16(ipfx + (size_t)(t + P * U) * N,                             \
                  rb + (unsigned)((((d) + P) & (R - 1)) * 2 + 0) * 1024u);    \
            dma16(zpfx + (size_t)(t + P * U) * N,                             \
                  rb + (unsigned)((((d) + P) & (R - 1)) * 2 + 1) * 1024u);    \
        }                                                                     \
        __builtin_amdgcn_sched_barrier(0);                                    \
        t += U;                                                               \
    }

#define STAGE(d, K, PF, LD, ST) { WAITV(K); STAGE_BODY(d, PF, LD, ST) }

    // Iteration 0 (stages 0..15): stage 0 has no store; ramped waits.
    STAGE(0, 24, 1, 1, 0)  STAGE(1, 24, 1, 1, 1)  STAGE(2, 25, 1, 1, 1)
    STAGE(3, 26, 1, 1, 1)  STAGE(4, 27, 1, 1, 1)  STAGE(5, 28, 1, 1, 1)
    STAGE(6, 29, 1, 1, 1)  STAGE(7, 30, 1, 1, 1)  STAGE(8, 31, 1, 1, 1)
    STAGE(9, 32, 1, 1, 1)  STAGE(10, 33, 1, 1, 1) STAGE(11, 34, 1, 1, 1)
    STAGE(12, 35, 1, 1, 1) STAGE(13, 36, 1, 1, 1) STAGE(14, 36, 1, 1, 1)
    STAGE(15, 36, 1, 1, 1)

    // Steady iterations 1..30 (stages 16..495): K=36 throughout.
    for (int it = 1; it <= 30; ++it) {
        STAGE(0, 36, 1, 1, 1)  STAGE(1, 36, 1, 1, 1)  STAGE(2, 36, 1, 1, 1)
        STAGE(3, 36, 1, 1, 1)  STAGE(4, 36, 1, 1, 1)  STAGE(5, 36, 1, 1, 1)
        STAGE(6, 36, 1, 1, 1)  STAGE(7, 36, 1, 1, 1)  STAGE(8, 36, 1, 1, 1)
        STAGE(9, 36, 1, 1, 1)  STAGE(10, 36, 1, 1, 1) STAGE(11, 36, 1, 1, 1)
        STAGE(12, 36, 1, 1, 1) STAGE(13, 36, 1, 1, 1) STAGE(14, 36, 1, 1, 1)
        STAGE(15, 36, 1, 1, 1)
    }

    // Final iteration (stages 496..511): prefetch stops after chunk 511
    // (stage 497); tail waits K = 1032-2d; last stage needs no wait and
    // loads no next chunk.
    STAGE(0, 36, 1, 1, 1)   STAGE(1, 36, 1, 1, 1)   STAGE(2, 36, 0, 1, 1)
    STAGE(3, 34, 0, 1, 1)   STAGE(4, 32, 0, 1, 1)   STAGE(5, 30, 0, 1, 1)
    STAGE(6, 28, 0, 1, 1)   STAGE(7, 26, 0, 1, 1)   STAGE(8, 24, 0, 1, 1)
    STAGE(9, 22, 0, 1, 1)   STAGE(10, 20, 0, 1, 1)  STAGE(11, 18, 0, 1, 1)
    STAGE(12, 16, 0, 1, 1)  STAGE(13, 14, 0, 1, 1)  STAGE(14, 12, 0, 1, 1)
    STAGE_BODY(15, 0, 0, 1)

    // Epilogue: store chunk 511's spikes (sbuf set 511&1 = 1).
    {
        f4v sv = *reinterpret_cast<const f4v*>(&sbuf[1][g][c4]);
        __builtin_nontemporal_store(
            sv, reinterpret_cast<f4v*>(opfx + (size_t)(T - U) * N));
    }

#undef STAGE
#undef STAGE_BODY
}

extern "C" void kernel_launch(void* const* d_in, const int* in_sizes, int n_in,
                              void* d_out, int out_size, void* d_ws, size_t ws_size,
                              hipStream_t stream) {
    const float* input_current = (const float*)d_in[0];
    const float* noise         = (const float*)d_in[1];
    float* out                 = (float*)d_out;

    TorchLIFNeuronGroup_85152021610615_kernel<<<N / 64, 64, 0, stream>>>(
        input_current, noise, out);
}

// Round 6
// 312.263 us; speedup vs baseline: 1.0574x; 1.0086x over previous
//
#include <hip/hip_runtime.h>

// LIF neuron scan: 16384 neurons x 2048 sequential steps, 1 thread/neuron,
// 256 waves = 1 wave/CU (structural).
//
// History:
//  R3  register ring (scalar dword loads), 106 us, 2.5 TB/s: vmcnt-slot cap.
//  R4-R8 LDS-DMA (global_load_lds) variants: 129-165 us. All collapse to ~1
//      HBM round trip per stage regardless of counted waits -> conclusion:
//      the per-DMA s_mov m0 rewrite interlocks with outstanding LDS-DMA
//      (m0 consumed at data-return, not latched at issue) => LDS-DMA cannot
//      be deep-pipelined per-wave. Abandoned.
//
// R9: register-staged pipeline, NO asm, NO m0, NO manual waitcnt:
//  - gI/gZ[16] f4v register ring (128 VGPR): stage d issues 2 NT dwordx4
//    loads for chunk d+16 (lane l holds row g=l>>4, cols 4(l&15)..+3).
//  - chunk d+1: 2 x ds_write_b128 into 2-deep LDS ping-pong (linear,
//    lane*16B), then 8 x ds_read_b32 transpose into compute regs cc[2][8]
//    (read stride 256B: 2 lanes/bank = conflict-free). Consumed next stage.
//  - spikes: thread writes 4 x b32 into sbuf ping-pong; NEXT stage b128-reads
//    the previous chunk's sbuf and emits ONE NT float4 store (store lags one
//    stage; write->read round trip spans the stage boundary).
//  => 3 vmem ops/stage (2 loads + 1 store). The ds_write's register use of
//    gI/gZ[slot] makes SIInsertWaitcnt emit a PRECISE vmcnt(~45) wait for
//    loads issued 15 stages earlier: 30 KB in flight per wave, 7.7 MB chip-
//    wide. All ordering compiler-derived (same-wave DS ops are in-order; no
//    aliasing ambiguity). sched_barrier(0) pins stage boundaries so the ring
//    cannot be collapsed (R2 lesson); all indices compile-time (no scratch).
//
// Exactness (binary spike output): contract(off), reference op order:
//   V = (V + 0.05f*(I-V)) + nz ; s = V>=Vth ; V = s?0:V ;
//   Vth = s ? min(max(Vth+0.1f,0.5f),2.0f) : Vth

constexpr int N = 16384;    // neurons
constexpr int T = 2048;     // sequential steps
constexpr int U = 4;        // timesteps per chunk
constexpr int C = T / U;    // 512 chunks
constexpr int P = 16;       // register-ring depth = prefetch distance
constexpr int NB = C / P;   // 32 blocks of P stages

static_assert(C == NB * P, "schedule geometry");

typedef float f4v __attribute__((ext_vector_type(4)));

__global__
__attribute__((amdgpu_flat_work_group_size(64, 64)))
__attribute__((amdgpu_waves_per_eu(1, 1)))
void TorchLIFNeuronGroup_85152021610615_kernel(const float* __restrict__ I,
                                               const float* __restrict__ Z,
                                               float* __restrict__ O) {
    #pragma clang fp contract(off)
    __shared__ __align__(16) float Ibuf[2][U][64];   // input ping-pong
    __shared__ __align__(16) float Zbuf[2][U][64];
    __shared__ __align__(16) float sbuf[2][U][64];   // spike ping-pong

    const int lane = threadIdx.x;
    const int g    = lane >> 4;          // row within chunk (0..3)
    const int c4   = (lane & 15) << 2;   // col group (0,4,..,60)
    const size_t laneOff = (size_t)g * N + c4;

    const float* ipfx = I + (size_t)blockIdx.x * 64 + laneOff;
    const float* zpfx = Z + (size_t)blockIdx.x * 64 + laneOff;
    float*       opfx = O + (size_t)blockIdx.x * 64 + laneOff;

    float V   = 0.0f;   // V_RESET
    float Vth = 1.0f;   // V_TH0
    f4v   gI[P], gZ[P]; // register ring (chunk c -> slot c%P), 128 VGPR
    float cc[2][8];     // transposed compute regs [parity][I0..3,Z0..3]

    // Prologue: issue NT loads for chunks 0..P-1 into slots 0..P-1.
    #pragma unroll
    for (int c = 0; c < P; ++c) {
        gI[c] = __builtin_nontemporal_load(
            reinterpret_cast<const f4v*>(ipfx + (size_t)(c * U) * N));
        gZ[c] = __builtin_nontemporal_load(
            reinterpret_cast<const f4v*>(zpfx + (size_t)(c * U) * N));
    }
    // Stage chunk 0 through LDS into cc[0] (compiler waits vmcnt precisely).
    *reinterpret_cast<f4v*>(&Ibuf[0][0][0] + lane * 4) = gI[0];
    *reinterpret_cast<f4v*>(&Zbuf[0][0][0] + lane * 4) = gZ[0];
    #pragma unroll
    for (int u = 0; u < U; ++u) {
        cc[0][u]     = Ibuf[0][u][lane];
        cc[0][4 + u] = Zbuf[0][u][lane];
    }

    int t = 0;  // timestep base of the chunk being computed (= 4*d)

    // Stage d (j = d mod P, compile-time):
    //  C: b128 read of chunk d-1 spikes from sbuf[(j+1)&1]   (CE)
    //  A: ds_write chunk d+1 from ring slot (j+1)  [vmcnt wait lands here]
    //  B: 8 ds_read -> cc[(j+1)&1]                            (AB)
    //  D: compute chunk d from cc[j&1]; 4 b32 spike writes -> sbuf[j&1]
    //  E: ONE NT float4 store of chunk d-1                    (CE)
    //  F: 2 NT dwordx4 loads chunk d+P -> ring slot j         (PF)
#define STAGE(j, CE, AB, PF)                                                  \
    {                                                                         \
        f4v sv{};                                                             \
        if (CE) sv = *reinterpret_cast<const f4v*>(                           \
                         &sbuf[((j) + 1) & 1][0][0] + lane * 4);              \
        if (AB) {                                                             \
            *reinterpret_cast<f4v*>(&Ibuf[((j) + 1) & 1][0][0] + lane * 4) =  \
                gI[((j) + 1) & (P - 1)];                                      \
            *reinterpret_cast<f4v*>(&Zbuf[((j) + 1) & 1][0][0] + lane * 4) =  \
                gZ[((j) + 1) & (P - 1)];                                      \
            _Pragma("unroll")                                                 \
            for (int u = 0; u < U; ++u) {                                     \
                cc[((j) + 1) & 1][u]     = Ibuf[((j) + 1) & 1][u][lane];      \
                cc[((j) + 1) & 1][4 + u] = Zbuf[((j) + 1) & 1][u][lane];      \
            }                                                                 \
        }                                                                     \
        _Pragma("unroll")                                                     \
        for (int u = 0; u < U; ++u) {                                         \
            float Iv = cc[(j) & 1][u];                                        \
            float Zv = cc[(j) & 1][4 + u];                                    \
            float dd = Iv - V;                                                \
            float v1 = V + 0.05f * dd;          /* DT/TAU */                  \
            float v2 = v1 + Zv;                                               \
            bool  s  = (v2 >= Vth);                                           \
            V = s ? 0.0f : v2;                                                \
            float nth = fminf(fmaxf(Vth + 0.1f, 0.5f), 2.0f);                 \
            Vth = s ? nth : Vth;                                              \
            sbuf[(j) & 1][u][lane] = s ? 1.0f : 0.0f;                         \
        }                                                                     \
        if (CE) __builtin_nontemporal_store(                                  \
                    sv, reinterpret_cast<f4v*>(opfx + (size_t)(t - U) * N));  \
        if (PF) {                                                             \
            gI[(j) & (P - 1)] = __builtin_nontemporal_load(                   \
                reinterpret_cast<const f4v*>(ipfx + (size_t)(t + P * U) * N));\
            gZ[(j) & (P - 1)] = __builtin_nontemporal_load(                   \
                reinterpret_cast<const f4v*>(zpfx + (size_t)(t + P * U) * N));\
        }                                                                     \
        __builtin_amdgcn_sched_barrier(0);                                    \
        t += U;                                                               \
    }

    // Block 0 (stages 0..15): stage 0 has no d-1 spikes to store.
    STAGE(0, 0, 1, 1)   STAGE(1, 1, 1, 1)   STAGE(2, 1, 1, 1)
    STAGE(3, 1, 1, 1)   STAGE(4, 1, 1, 1)   STAGE(5, 1, 1, 1)
    STAGE(6, 1, 1, 1)   STAGE(7, 1, 1, 1)   STAGE(8, 1, 1, 1)
    STAGE(9, 1, 1, 1)   STAGE(10, 1, 1, 1)  STAGE(11, 1, 1, 1)
    STAGE(12, 1, 1, 1)  STAGE(13, 1, 1, 1)  STAGE(14, 1, 1, 1)
    STAGE(15, 1, 1, 1)

    // Blocks 1..30 (stages 16..495): steady state.
    #pragma clang loop unroll(disable)
    for (int k = 1; k <= NB - 2; ++k) {
        STAGE(0, 1, 1, 1)   STAGE(1, 1, 1, 1)   STAGE(2, 1, 1, 1)
        STAGE(3, 1, 1, 1)   STAGE(4, 1, 1, 1)   STAGE(5, 1, 1, 1)
        STAGE(6, 1, 1, 1)   STAGE(7, 1, 1, 1)   STAGE(8, 1, 1, 1)
        STAGE(9, 1, 1, 1)   STAGE(10, 1, 1, 1)  STAGE(11, 1, 1, 1)
        STAGE(12, 1, 1, 1)  STAGE(13, 1, 1, 1)  STAGE(14, 1, 1, 1)
        STAGE(15, 1, 1, 1)
    }

    // Block 31 (stages 496..511): no more prefetch (chunks >511 don't
    // exist); stage 511 stages no chunk 512.
    STAGE(0, 1, 1, 0)   STAGE(1, 1, 1, 0)   STAGE(2, 1, 1, 0)
    STAGE(3, 1, 1, 0)   STAGE(4, 1, 1, 0)   STAGE(5, 1, 1, 0)
    STAGE(6, 1, 1, 0)   STAGE(7, 1, 1, 0)   STAGE(8, 1, 1, 0)
    STAGE(9, 1, 1, 0)   STAGE(10, 1, 1, 0)  STAGE(11, 1, 1, 0)
    STAGE(12, 1, 1, 0)  STAGE(13, 1, 1, 0)  STAGE(14, 1, 1, 0)
    STAGE(15, 1, 0, 0)

    // Epilogue: store chunk 511's spikes (computed at stage 511, parity 1).
    {
        f4v sv = *reinterpret_cast<const f4v*>(&sbuf[1][0][0] + lane * 4);
        __builtin_nontemporal_store(
            sv, reinterpret_cast<f4v*>(opfx + (size_t)(T - U) * N));
    }

#undef STAGE
}

extern "C" void kernel_launch(void* const* d_in, const int* in_sizes, int n_in,
                              void* d_out, int out_size, void* d_ws, size_t ws_size,
                              hipStream_t stream) {
    const float* input_current = (const float*)d_in[0];
    const float* noise         = (const float*)d_in[1];
    float* out                 = (float*)d_out;

    TorchLIFNeuronGroup_85152021610615_kernel<<<N / 64, 64, 0, stream>>>(
        input_current, noise, out);
}

// Round 7
// 289.459 us; speedup vs baseline: 1.1407x; 1.0788x over previous
//
#include <hip/hip_runtime.h>

// LIF neuron scan: 16384 neurons x 2048 sequential steps.
//
// R10: producer/consumer wave specialization. R3/R9 both converge to
// ~180 ns/stage because ONE wave serially issues loads, waits vmcnt,
// stages LDS, computes, and retires NT stores with 1 wave/SIMD and no
// TLP. Split roles over 4 waves (256-thread block, 64 neurons/block,
// 256 blocks = 256 CUs):
//   w0: I-producer  (NT dwordx4 -> 4 reg sets -> ds_write_b128)
//   w1: Z-producer  (same, Z stream)
//   w2: spike storer (ds_read_b128 ring -> NT dwordx4 stores)
//   w3: consumer    (pure scan: ds_read_b32 + VALU chain + spike writes)
// Sections of S=8 chunks (32 timesteps); 64 sections; per-section sync via
// raw s_barrier + lgkmcnt(0) ONLY -- __syncthreads() would drain vmcnt(0)
// and destroy the producers' in-flight pipeline (the GEMM barrier-drain
// stall). Producers load section k+3 at iter k, ds_write section k+1 from
// regs loaded at iter k-2 (vmcnt wait is a precise register dep: ~1.3 us
// latency cover; 2 waves x ~24 KB in flight per CU = ~10 MB chip-wide).
// LDS ring: 2 sections x {I,Z} (32 KB) + 2-section spike buffer (16 KB).
// Consumer reads stride-256B b32 (2 lanes/bank = free); storer reads the
// spike chunk linearly (b128) and stores with the row/col lane mapping.
//
// Expected: time = max(consumer ~25-32 us, HBM floor ~43 us) + ramp.
//
// Exactness (binary spike output): contract(off), reference op order:
//   V = (V + 0.05f*(I-V)) + nz ; s = V>=Vth ; V = s?0:V ;
//   Vth = s ? min(max(Vth+0.1f,0.5f),2.0f) : Vth

constexpr int N  = 16384;   // neurons
constexpr int T  = 2048;    // sequential steps
constexpr int U  = 4;       // timesteps per chunk
constexpr int CH = T / U;   // 512 chunks
constexpr int S  = 8;       // chunks per section
constexpr int NSEC = CH / S;// 64 sections

static_assert(NSEC % 4 == 0, "j-unroll of 4 needs NSEC % 4 == 0");

typedef float f4v __attribute__((ext_vector_type(4)));

// Raw barrier: drain LDS ops (visibility to other waves), do NOT drain
// vmcnt (keeps producer loads / storer stores in flight across sections).
#define BAR() do {                                                            \
    asm volatile("s_waitcnt lgkmcnt(0)" ::: "memory");                        \
    __builtin_amdgcn_s_barrier();                                             \
    __builtin_amdgcn_sched_barrier(0);                                        \
} while (0)

__global__
__attribute__((amdgpu_flat_work_group_size(256, 256)))
void TorchLIFNeuronGroup_85152021610615_kernel(const float* __restrict__ I,
                                               const float* __restrict__ Z,
                                               float* __restrict__ O) {
    #pragma clang fp contract(off)
    // IZ[parity][stream][chunk][row][col] ; SB[parity][chunk][row][col]
    __shared__ __align__(16) float IZ[2][2][S][U][64];
    __shared__ __align__(16) float SB[2][S][U][64];

    const int w    = threadIdx.x >> 6;   // wave role
    const int lane = threadIdx.x & 63;
    const int g    = lane >> 4;          // row within chunk (0..3)
    const int c4   = (lane & 15) << 2;   // col group (0,4,..,60)
    const size_t laneOff = (size_t)g * N + c4;
    const size_t nbase   = (size_t)blockIdx.x * 64;

    const float* pfx  = (w == 0 ? I : Z) + nbase + laneOff;  // producers
    float*       opfx = O + nbase + laneOff;                 // storer

    float V   = 0.0f;   // consumer state
    float Vth = 1.0f;
    f4v rg[4][S];       // producer register sets (section s -> set s&3)
    f4v sv[S];          // storer staging regs

    // ---- Prologue: producers load sections 0..2, ds_write section 0. ----
    if (w <= 1) {
        #pragma unroll
        for (int s = 0; s < 3; ++s)
            #pragma unroll
            for (int c = 0; c < S; ++c)
                rg[s][c] = __builtin_nontemporal_load(
                    reinterpret_cast<const f4v*>(
                        pfx + (size_t)(U * (S * s + c)) * N));
        #pragma unroll
        for (int c = 0; c < S; ++c)
            *reinterpret_cast<f4v*>(&IZ[0][w][c][0][0] + lane * 4) = rg[0][c];
    }
    BAR();

    // ---- Main: 64 sections, j-unrolled by 4 so all &3/&1 are static. ----
    #pragma clang loop unroll(disable)
    for (int kb = 0; kb < NSEC / 4; ++kb) {
        #pragma unroll
        for (int j = 0; j < 4; ++j) {
            const int k = kb * 4 + j;    // section being computed
            if (w <= 1) {
                // ds_write section k+1 (regs loaded at iter k-2; the
                // compiler emits a precise vmcnt wait on rg[(j+1)&3]).
                if (k <= NSEC - 2) {
                    #pragma unroll
                    for (int c = 0; c < S; ++c)
                        *reinterpret_cast<f4v*>(
                            &IZ[(j + 1) & 1][w][c][0][0] + lane * 4) =
                            rg[(j + 1) & 3][c];
                }
                // issue NT loads for section k+3 into set (j+3)&3.
                if (k <= NSEC - 4) {
                    #pragma unroll
                    for (int c = 0; c < S; ++c)
                        rg[(j + 3) & 3][c] = __builtin_nontemporal_load(
                            reinterpret_cast<const f4v*>(
                                pfx + (size_t)(U * (S * (k + 3) + c)) * N));
                }
            } else if (w == 2) {
                // store section k-1 spikes (written by consumer at iter k-1).
                if (k >= 1) {
                    #pragma unroll
                    for (int c = 0; c < S; ++c)
                        sv[c] = *reinterpret_cast<const f4v*>(
                            &SB[(j + 1) & 1][c][0][0] + lane * 4);
                    #pragma unroll
                    for (int c = 0; c < S; ++c)
                        __builtin_nontemporal_store(sv[c],
                            reinterpret_cast<f4v*>(
                                opfx + (size_t)(U * (S * (k - 1) + c)) * N));
                }
            } else {
                // consumer: scan section k from IZ[j&1], 1-chunk read-ahead.
                float ci[2][U], cz[2][U];
                #pragma unroll
                for (int u = 0; u < U; ++u) {
                    ci[0][u] = IZ[j & 1][0][0][u][lane];
                    cz[0][u] = IZ[j & 1][1][0][u][lane];
                }
                #pragma unroll
                for (int c = 0; c < S; ++c) {
                    if (c + 1 < S) {
                        #pragma unroll
                        for (int u = 0; u < U; ++u) {
                            ci[(c + 1) & 1][u] = IZ[j & 1][0][c + 1][u][lane];
                            cz[(c + 1) & 1][u] = IZ[j & 1][1][c + 1][u][lane];
                        }
                    }
                    #pragma unroll
                    for (int u = 0; u < U; ++u) {
                        float Iv = ci[c & 1][u];
                        float Zv = cz[c & 1][u];
                        float dd = Iv - V;
                        float v1 = V + 0.05f * dd;          // DT/TAU
                        float v2 = v1 + Zv;
                        bool  s  = (v2 >= Vth);
                        V = s ? 0.0f : v2;
                        float nth = fminf(fmaxf(Vth + 0.1f, 0.5f), 2.0f);
                        Vth = s ? nth : Vth;
                        SB[j & 1][c][u][lane] = s ? 1.0f : 0.0f;
                    }
                }
            }
            BAR();
        }
    }

    // ---- Epilogue: store the last section's spikes (parity 63&1 = 1). ----
    if (w == 2) {
        #pragma unroll
        for (int c = 0; c < S; ++c)
            sv[c] = *reinterpret_cast<const f4v*>(
                &SB[1][c][0][0] + lane * 4);
        #pragma unroll
        for (int c = 0; c < S; ++c)
            __builtin_nontemporal_store(sv[c],
                reinterpret_cast<f4v*>(
                    opfx + (size_t)(U * (S * (NSEC - 1) + c)) * N));
    }
}

extern "C" void kernel_launch(void* const* d_in, const int* in_sizes, int n_in,
                              void* d_out, int out_size, void* d_ws, size_t ws_size,
                              hipStream_t stream) {
    const float* input_current = (const float*)d_in[0];
    const float* noise         = (const float*)d_in[1];
    float* out                 = (float*)d_out;

    TorchLIFNeuronGroup_85152021610615_kernel<<<N / 64, 256, 0, stream>>>(
        input_current, noise, out);
}